// Round 1
// baseline (774.125 us; speedup 1.0000x reference)
//
#include <hip/hip_runtime.h>

#define B_ 16
#define C_ 512
#define K_ 128
#define N_ 4096   // H*W = 64*64
#define NKEEP 51  // int(0.1 * 512)

// ---------------------------------------------------------------------------
// K1: depthwise 3x3 conv (SAME, stride 1) for k and v from x_kv.
// One thread per output pixel; computes both k and v from the same 3x3 reads.
__global__ void conv_kv_kernel(const float* __restrict__ xkv,
                               const float* __restrict__ wk, const float* __restrict__ bk,
                               const float* __restrict__ wv, const float* __restrict__ bv,
                               float* __restrict__ kb, float* __restrict__ vb) {
    int idx = blockIdx.x * 256 + threadIdx.x;   // over B*K*H*W = 8388608
    int x = idx & 63;
    int y = (idx >> 6) & 63;
    int k = (idx >> 12) & 127;
    int b = idx >> 19;
    const float* wkp = wk + k * 9;
    const float* wvp = wv + k * 9;
    const float* xp  = xkv + (size_t)(b * K_ + k) * N_;
    float ak = bk[k], av = bv[k];
#pragma unroll
    for (int dy = 0; dy < 3; ++dy) {
        int yy = y + dy - 1;
        if (yy < 0 || yy > 63) continue;
#pragma unroll
        for (int dx = 0; dx < 3; ++dx) {
            int xx = x + dx - 1;
            if (xx < 0 || xx > 63) continue;
            float xv = xp[yy * 64 + xx];
            ak += xv * wkp[dy * 3 + dx];
            av += xv * wvp[dy * 3 + dx];
        }
    }
    kb[idx] = ak;
    vb[idx] = av;
}

// ---------------------------------------------------------------------------
// K2: logits[b, c, k] = dot(q[b,c,:], kbuf[b,k,:]) / sqrt(128)
// q is computed on the fly (depthwise conv on x_q) during A-tile staging.
// Block: one (b, 16-channel tile). Inner dim n chunked by image row (64 px).
__global__ __launch_bounds__(256) void qk_kernel(const float* __restrict__ xq,
                                                 const float* __restrict__ wq,
                                                 const float* __restrict__ bq,
                                                 const float* __restrict__ kb,
                                                 float* __restrict__ aw) {
    __shared__ float qs[64][20];    // [x][c], pad 16->20
    __shared__ float ks[64][132];   // [x][k], pad 128->132
    int blk = blockIdx.x;
    int ct = blk & 31;             // 32 c-tiles of 16
    int b  = blk >> 5;
    int c0 = ct * 16;
    int tid = threadIdx.x;

    // staging roles
    int c_l = tid >> 4;            // 0..15 (q conv channel)
    int xb  = (tid & 15) * 4;      // q conv x-base (4 pixels)
    int k_l = tid >> 1;            // 0..127 (k row)
    int xh  = (tid & 1) * 32;      // k row half
    // compute roles: 8 c-groups x 32 k-groups
    int cg = tid & 7;              // cbase = 2*cg
    int kg = tid >> 3;             // kbase = 4*kg

    // preload this thread's conv weights
    float w0,w1,w2,w3,w4,w5,w6,w7,w8, bias;
    {
        const float* wp = wq + (size_t)(c0 + c_l) * 9;
        w0=wp[0]; w1=wp[1]; w2=wp[2]; w3=wp[3]; w4=wp[4]; w5=wp[5]; w6=wp[6]; w7=wp[7]; w8=wp[8];
        bias = bq[c0 + c_l];
    }
    const float* xqp = xq + (size_t)(b * C_ + c0 + c_l) * N_;
    const float* kbp = kb + (size_t)(b * K_ + k_l) * N_;

    float acc[2][4];
#pragma unroll
    for (int i = 0; i < 2; ++i)
#pragma unroll
        for (int j = 0; j < 4; ++j) acc[i][j] = 0.f;

    for (int r = 0; r < 64; ++r) {
        __syncthreads();
        // ---- stage ks: row r of k-plane k_l, 32 x-positions ----
        {
            const float4* src = (const float4*)(kbp + r * 64 + xh);
#pragma unroll
            for (int m = 0; m < 8; ++m) {
                float4 v = src[m];
                int xx = xh + m * 4;
                ks[xx][k_l] = v.x; ks[xx + 1][k_l] = v.y;
                ks[xx + 2][k_l] = v.z; ks[xx + 3][k_l] = v.w;
            }
        }
        // ---- stage qs: conv on the fly, 4 pixels of row r, channel c_l ----
#pragma unroll
        for (int i = 0; i < 4; ++i) {
            int x = xb + i;
            float a = bias;
#pragma unroll
            for (int dy = 0; dy < 3; ++dy) {
                int yy = r + dy - 1;
                if (yy < 0 || yy > 63) continue;
                const float* row = xqp + yy * 64;
                float ww0 = (dy == 0) ? w0 : (dy == 1) ? w3 : w6;
                float ww1 = (dy == 0) ? w1 : (dy == 1) ? w4 : w7;
                float ww2 = (dy == 0) ? w2 : (dy == 1) ? w5 : w8;
                if (x > 0)  a += row[x - 1] * ww0;
                a += row[x] * ww1;
                if (x < 63) a += row[x + 1] * ww2;
            }
            qs[x][c_l] = a;
        }
        __syncthreads();
        // ---- accumulate 2c x 4k outer products over this row ----
#pragma unroll 4
        for (int nn = 0; nn < 64; ++nn) {
            float2 qv = *(const float2*)&qs[nn][cg * 2];
            float4 kv = *(const float4*)&ks[nn][kg * 4];
            acc[0][0] += qv.x * kv.x; acc[0][1] += qv.x * kv.y;
            acc[0][2] += qv.x * kv.z; acc[0][3] += qv.x * kv.w;
            acc[1][0] += qv.y * kv.x; acc[1][1] += qv.y * kv.y;
            acc[1][2] += qv.y * kv.z; acc[1][3] += qv.y * kv.w;
        }
    }
    const float scale = 0.08838834764831845f; // 1/sqrt(128)
#pragma unroll
    for (int i = 0; i < 2; ++i) {
        int c = c0 + cg * 2 + i;
        float* dst = aw + (size_t)(b * C_ + c) * K_ + kg * 4;
#pragma unroll
        for (int j = 0; j < 4; ++j) dst[j] = acc[i][j] * scale;
    }
}

// ---------------------------------------------------------------------------
// K3: softmax over k (128) per (b,c) row. One wave per row.
__global__ void softmax_kernel(float* __restrict__ aw) {
    int tid  = threadIdx.x;
    int wave = tid >> 6;
    int lane = tid & 63;
    int row  = blockIdx.x * 4 + wave;   // over B*C = 8192
    float* p = aw + (size_t)row * K_;
    float v0 = p[lane], v1 = p[lane + 64];
    float m = fmaxf(v0, v1);
#pragma unroll
    for (int s = 32; s >= 1; s >>= 1) m = fmaxf(m, __shfl_xor(m, s, 64));
    float e0 = __expf(v0 - m), e1 = __expf(v1 - m);
    float s = e0 + e1;
#pragma unroll
    for (int t = 32; t >= 1; t >>= 1) s += __shfl_xor(s, t, 64);
    float inv = 1.0f / s;
    p[lane] = e0 * inv;
    p[lane + 64] = e1 * inv;
}

// ---------------------------------------------------------------------------
// K4: per (b,k) column over c (512): find 51st-largest exactly via binary
// search on float bit pattern (positive floats order as uints), zero the rest.
__global__ void topk_mask_kernel(float* __restrict__ aw) {
    int tid  = threadIdx.x;
    int wave = tid >> 6, lane = tid & 63;
    int col  = blockIdx.x * 4 + wave;   // over B*K = 2048
    int b = col >> 7, k = col & 127;
    float* base = aw + (size_t)(b * C_) * K_ + k;
    unsigned u[8];
#pragma unroll
    for (int j = 0; j < 8; ++j)
        u[j] = __float_as_uint(base[(size_t)(j * 64 + lane) * K_]);
    unsigned T = 0;
#pragma unroll
    for (int bit = 31; bit >= 0; --bit) {
        unsigned cand = T | (1u << bit);
        int cnt = 0;
#pragma unroll
        for (int j = 0; j < 8; ++j) cnt += (u[j] >= cand) ? 1 : 0;
#pragma unroll
        for (int s = 32; s >= 1; s >>= 1) cnt += __shfl_xor(cnt, s, 64);
        if (cnt >= NKEEP) T = cand;
    }
#pragma unroll
    for (int j = 0; j < 8; ++j)
        if (u[j] < T) base[(size_t)(j * 64 + lane) * K_] = 0.0f;
}

// ---------------------------------------------------------------------------
// K5: attn_out = aw_masked @ v ; out0 = x_q + attn_out.
// Block tile: 32 c x 256 n, inner k chunked by 16.
__global__ __launch_bounds__(256) void av_kernel(const float* __restrict__ aw,
                                                 const float* __restrict__ vb,
                                                 const float* __restrict__ xq,
                                                 float* __restrict__ out) {
    __shared__ float vs[16][260];   // [k][n], pad 256->260
    __shared__ float aws[16][36];   // [k][c], pad 32->36
    int blk  = blockIdx.x;
    int b    = blk >> 8;
    int rest = blk & 255;
    int c0 = (rest >> 4) * 32;
    int n0 = (rest & 15) * 256;
    int tid = threadIdx.x;
    int cg = tid >> 5;              // 0..7, cbase = cg*4
    int ng = tid & 31;              // nbase = ng*8
    int k_l = tid >> 4;             // 0..15 (vs staging row)
    int nn0 = (tid & 15) * 16;

    float acc[4][8];
#pragma unroll
    for (int i = 0; i < 4; ++i)
#pragma unroll
        for (int j = 0; j < 8; ++j) acc[i][j] = 0.f;

    for (int kc = 0; kc < K_; kc += 16) {
        __syncthreads();
        // stage vs[k][n]: natural layout, float4
        {
            const float4* src = (const float4*)(vb + (size_t)(b * K_ + kc + k_l) * N_ + n0 + nn0);
            float4* dst = (float4*)&vs[k_l][nn0];
#pragma unroll
            for (int m = 0; m < 4; ++m) dst[m] = src[m];
        }
        // stage aws transposed: [k][c]
        {
            int i0 = tid * 2;
#pragma unroll
            for (int t2 = 0; t2 < 2; ++t2) {
                int i = i0 + t2;
                int cc = i >> 4;    // 0..31
                int kk = i & 15;
                aws[kk][cc] = aw[(size_t)(b * C_ + c0 + cc) * K_ + kc + kk];
            }
        }
        __syncthreads();
#pragma unroll
        for (int kk = 0; kk < 16; ++kk) {
            float4 a4  = *(const float4*)&aws[kk][cg * 4];
            float4 v4a = *(const float4*)&vs[kk][ng * 8];
            float4 v4b = *(const float4*)&vs[kk][ng * 8 + 4];
            float aa[4] = {a4.x, a4.y, a4.z, a4.w};
            float av[8] = {v4a.x, v4a.y, v4a.z, v4a.w, v4b.x, v4b.y, v4b.z, v4b.w};
#pragma unroll
            for (int i = 0; i < 4; ++i)
#pragma unroll
                for (int j = 0; j < 8; ++j) acc[i][j] += aa[i] * av[j];
        }
    }
    // epilogue: out = x_q + acc, vectorized
#pragma unroll
    for (int i = 0; i < 4; ++i) {
        int c = c0 + cg * 4 + i;
        size_t base = (size_t)(b * C_ + c) * N_ + n0 + ng * 8;
        const float4* xp4 = (const float4*)(xq + base);
        float4* op4 = (float4*)(out + base);
        float4 x0 = xp4[0], x1 = xp4[1];
        float4 o0, o1;
        o0.x = x0.x + acc[i][0]; o0.y = x0.y + acc[i][1];
        o0.z = x0.z + acc[i][2]; o0.w = x0.w + acc[i][3];
        o1.x = x1.x + acc[i][4]; o1.y = x1.y + acc[i][5];
        o1.z = x1.z + acc[i][6]; o1.w = x1.w + acc[i][7];
        op4[0] = o0; op4[1] = o1;
    }
}

// ---------------------------------------------------------------------------
extern "C" void kernel_launch(void* const* d_in, const int* in_sizes, int n_in,
                              void* d_out, int out_size, void* d_ws, size_t ws_size,
                              hipStream_t stream) {
    const float* xq  = (const float*)d_in[0];
    const float* xkv = (const float*)d_in[1];
    const float* wq  = (const float*)d_in[2];
    const float* bq  = (const float*)d_in[3];
    const float* wk  = (const float*)d_in[4];
    const float* bk  = (const float*)d_in[5];
    const float* wv  = (const float*)d_in[6];
    const float* bv  = (const float*)d_in[7];

    float* out0 = (float*)d_out;                       // [16,512,64,64]
    float* aw   = out0 + (size_t)B_ * C_ * N_;         // [16,512,128]

    float* kb = (float*)d_ws;                          // [16,128,4096]
    float* vb = kb + (size_t)B_ * K_ * N_;             // [16,128,4096]

    // 1. depthwise conv for k, v
    conv_kv_kernel<<<(B_ * K_ * N_) / 256, 256, 0, stream>>>(xkv, wk, bk, wv, bv, kb, vb);
    // 2. logits = (q . k) / sqrt(128), q conv fused
    qk_kernel<<<B_ * 32, 256, 0, stream>>>(xq, wq, bq, kb, aw);
    // 3. softmax over k
    softmax_kernel<<<(B_ * C_) / 4, 256, 0, stream>>>(aw);
    // 4. top-51 along c per (b,k), mask in place
    topk_mask_kernel<<<(B_ * K_) / 4, 256, 0, stream>>>(aw);
    // 5. attn_out = aw @ v + x_q
    av_kernel<<<B_ * 256, 256, 0, stream>>>(aw, vb, xq, out0);
}